// Round 1
// baseline (9790.675 us; speedup 1.0000x reference)
//
#include <hip/hip_runtime.h>

// DeepAR on MI355X: sequential T=160 scan, per-step fused bf16-MFMA LSTM kernels.
// B=128, T=160, F=512, E=64, H=1024, L=2. Output [B,T,2] fp32.
//
// Design notes (round 1):
//  - Two kernels per step (kA: LSTM0 + mu finalize/label build, kB: LSTM1),
//    stream-ordered => cross-XCD visibility at kernel boundaries, no grid sync.
//  - Weights pre-packed bf16: row pr = wgn*32 + (4j+q) maps to original row
//    q*1024 + wgn*8 + j, K-contiguous => 16B B-frag loads.
//  - Partials / h-state parity double-buffered (t&1) to avoid WAR races.
//  - mask dtype auto-detected (int32 / float32 / bytes) by a probe kernel.

#define B_  128
#define T_  160
#define FD  512
#define E_  64
#define H_  1024
#define G4  4096

typedef unsigned short ushort_t;
typedef __attribute__((ext_vector_type(8))) short bf16x8;
typedef __attribute__((ext_vector_type(4))) float f32x4;

__device__ __forceinline__ bf16x8 ld8(const ushort_t* p) {
    return *reinterpret_cast<const bf16x8*>(p);
}
__device__ __forceinline__ f32x4 mfma16(bf16x8 a, bf16x8 b, f32x4 c) {
    return __builtin_amdgcn_mfma_f32_16x16x32_bf16(a, b, c, 0, 0, 0);
}
__device__ __forceinline__ ushort_t f2bf(float x) {
    unsigned u = __float_as_uint(x);
    u += 0x7FFFu + ((u >> 16) & 1u);   // RNE
    return (ushort_t)(u >> 16);
}
__device__ __forceinline__ float sigm(float x)  { return 1.f / (1.f + __expf(-x)); }
__device__ __forceinline__ float tanh_(float x) { return 1.f - 2.f / (__expf(2.f * x) + 1.f); }
__device__ __forceinline__ float softp(float x) { return x > 20.f ? x : log1pf(__expf(x)); }

// ---------------- prologue kernels ----------------

// classify mask buffer: flags[0]=nonbinary-words, flags[1]=non-float-words
__global__ void detect_mask(const unsigned* __restrict__ m, int* __restrict__ flags) {
    int i = blockIdx.x * 256 + threadIdx.x;   // scan first 5120 words (safe in all interps)
    unsigned w = m[i];
    if (w > 1u) atomicOr(&flags[0], 1);
    if (w != 0u && w != 0x3F800000u) atomicOr(&flags[1], 1);
}

__global__ void pack0(const float* __restrict__ Wih0, const float* __restrict__ Whh0,
                      ushort_t* __restrict__ Wp0) {
    for (int i = blockIdx.x * 256 + threadIdx.x; i < G4 * 1600; i += gridDim.x * 256) {
        int pr = i / 1600;
        int k  = i - pr * 1600;
        int wgn = pr >> 5, r = pr & 31;
        int j = r >> 2, q = r & 3;
        int row = q * 1024 + wgn * 8 + j;
        float v = (k < 576) ? Wih0[row * 576 + k] : Whh0[row * 1024 + (k - 576)];
        Wp0[i] = f2bf(v);
    }
}

__global__ void pack1(const float* __restrict__ Wih1, const float* __restrict__ Whh1,
                      ushort_t* __restrict__ Wp1) {
    for (int i = blockIdx.x * 256 + threadIdx.x; i < G4 * 2048; i += gridDim.x * 256) {
        int pr = i >> 11;
        int k  = i & 2047;
        int wgn = pr >> 5, r = pr & 31;
        int j = r >> 2, q = r & 3;
        int row = q * 1024 + wgn * 8 + j;
        float v = (k < 1024) ? Wih1[row * 1024 + k] : Whh1[row * 1024 + (k - 1024)];
        Wp1[i] = f2bf(v);
    }
}

__global__ void bsumk(const float* __restrict__ a0, const float* __restrict__ b0,
                      const float* __restrict__ a1, const float* __restrict__ b1,
                      float* __restrict__ o0, float* __restrict__ o1) {
    int i = blockIdx.x * 256 + threadIdx.x;
    if (i < G4) { o0[i] = a0[i] + b0[i]; o1[i] = a1[i] + b1[i]; }
}

// feat [B][T][512] fp32 -> featbf [T][B][512] bf16
__global__ void featconv(const float* __restrict__ feat, ushort_t* __restrict__ fb) {
    int i = blockIdx.x * 256 + threadIdx.x;   // [0, 160*128*128) float4 units
    int kv = i & 127;
    int b  = (i >> 7) & 127;
    int t  = i >> 14;
    float4 v = reinterpret_cast<const float4*>(feat)[((size_t)(b * T_ + t)) * 128 + kv];
    ushort4 o = make_ushort4(f2bf(v.x), f2bf(v.y), f2bf(v.z), f2bf(v.w));
    reinterpret_cast<ushort4*>(fb)[((size_t)(t * B_ + b)) * 128 + kv] = o;
}

// ---------------- per-step kernels ----------------
// grid 256: wgm = blk>>7 (batch half, 64 rows), wgn = blk&127 (8 hidden units).
// Each wave (4/WG) does one 16-row M-tile x two 16-col N-tiles, K in chunks of 32.

__global__ __launch_bounds__(256) void kA(
    const ushort_t* __restrict__ Wp0, const float* __restrict__ bs0,
    const ushort_t* __restrict__ fb, const float* __restrict__ emb,
    const void* __restrict__ mask, const int* __restrict__ flags,
    const float* __restrict__ Wtgt, const float* __restrict__ btgt,
    const float* __restrict__ muw, const float* __restrict__ sgw,
    const float* __restrict__ mub, const float* __restrict__ sgb,
    float* __restrict__ c0, const ushort_t* __restrict__ h0r, ushort_t* __restrict__ h0w,
    const float* __restrict__ p0mu_r, const float* __restrict__ p0sg_r,
    const float* __restrict__ p1mu_r, const float* __restrict__ p1sg_r,
    float* __restrict__ p0mu_w, float* __restrict__ p0sg_w,
    float* __restrict__ out, int t)
{
    __shared__ float    red[64][4];
    __shared__ float    lmu[64];
    __shared__ ushort_t lab[64][72];   // 64 rows x 64 cols label tile, pad to 72 (16B-aligned rows)
    __shared__ float    gt[64][33];    // gate pre-activations

    const int tid    = threadIdx.x;
    const int blk    = blockIdx.x;
    const int wgm    = blk >> 7;
    const int wgn    = blk & 127;
    const int b_base = wgm * 64;
    const int h_base = wgn * 8;

    // ---- phase 1: finalize mu(t-1) (and sigma + out for wgn==0) ----
    if (t > 0) {
        int bl = tid >> 2, qq = tid & 3;
        const float4* pa = reinterpret_cast<const float4*>(p0mu_r + ((b_base + bl) * 128 + qq * 32));
        const float4* pb = reinterpret_cast<const float4*>(p1mu_r + ((b_base + bl) * 128 + qq * 32));
        float s = 0.f;
        #pragma unroll
        for (int i = 0; i < 8; ++i) {
            float4 x = pa[i], y = pb[i];
            s += (x.x + x.y) + (x.z + x.w) + (y.x + y.y) + (y.z + y.w);
        }
        red[bl][qq] = s;
        __syncthreads();
        if (tid < 64) lmu[tid] = red[tid][0] + red[tid][1] + red[tid][2] + red[tid][3] + mub[0];
        __syncthreads();
        if (wgn == 0) {   // block-uniform branch
            const float4* pc = reinterpret_cast<const float4*>(p0sg_r + ((b_base + bl) * 128 + qq * 32));
            const float4* pd = reinterpret_cast<const float4*>(p1sg_r + ((b_base + bl) * 128 + qq * 32));
            float s2 = 0.f;
            #pragma unroll
            for (int i = 0; i < 8; ++i) {
                float4 x = pc[i], y = pd[i];
                s2 += (x.x + x.y) + (x.z + x.w) + (y.x + y.y) + (y.z + y.w);
            }
            red[bl][qq] = s2;
            __syncthreads();
            if (tid < 64) {
                int b = b_base + tid;
                float sg = softp(red[tid][0] + red[tid][1] + red[tid][2] + red[tid][3] + sgb[0]);
                out[(b * T_ + (t - 1)) * 2 + 0] = lmu[tid];
                out[(b * T_ + (t - 1)) * 2 + 1] = sg;
            }
        }
    }

    // ---- phase 2: build label tile (mu-embed where masked, else embeddings) ----
    {
        const int nonbin = flags[0], nonfl = flags[1];
        for (int e = tid; e < 64 * E_; e += 256) {
            int bl = e >> 6, cc = e & 63;
            int b = b_base + bl;
            bool um = false;
            if (t > 0) {
                int mi = b * T_ + t;
                if (!nonbin)     um = reinterpret_cast<const int*>(mask)[mi] != 0;
                else if (!nonfl) um = reinterpret_cast<const float*>(mask)[mi] != 0.f;
                else             um = reinterpret_cast<const unsigned char*>(mask)[mi] != 0;
            }
            float v = um ? (lmu[bl] * Wtgt[cc] + btgt[cc]) : emb[(b * T_ + t) * E_ + cc];
            lab[bl][cc] = f2bf(v);
        }
    }
    __syncthreads();

    // ---- phase 3: GEMM gates0 = [feat | lab | h0prev] @ Wp0^T ----
    const int w    = tid >> 6;
    const int lane = tid & 63;
    const int quad = lane >> 4;
    const int l16  = lane & 15;
    const int ko   = quad * 8;
    const int arow = b_base + w * 16 + l16;

    f32x4 acc0 = {0.f, 0.f, 0.f, 0.f};
    f32x4 acc1 = {0.f, 0.f, 0.f, 0.f};

    const ushort_t* aF  = fb + ((size_t)(t * B_ + arow)) * FD + ko;
    const ushort_t* br0 = Wp0 + ((size_t)(wgn * 32 + l16)) * 1600 + ko;
    const ushort_t* br1 = Wp0 + ((size_t)(wgn * 32 + 16 + l16)) * 1600 + ko;

    #pragma unroll 4
    for (int kc = 0; kc < FD; kc += 32) {
        bf16x8 a = ld8(aF + kc);
        acc0 = mfma16(a, ld8(br0 + kc), acc0);
        acc1 = mfma16(a, ld8(br1 + kc), acc1);
    }
    {
        const ushort_t* aL = &lab[w * 16 + l16][ko];
        #pragma unroll
        for (int kc = 0; kc < 64; kc += 32) {
            bf16x8 a = *reinterpret_cast<const bf16x8*>(aL + kc);
            acc0 = mfma16(a, ld8(br0 + 512 + kc), acc0);
            acc1 = mfma16(a, ld8(br1 + 512 + kc), acc1);
        }
    }
    if (t > 0) {
        const ushort_t* aH = h0r + (size_t)arow * H_ + ko;
        #pragma unroll 4
        for (int kc = 0; kc < H_; kc += 32) {
            bf16x8 a = ld8(aH + kc);
            acc0 = mfma16(a, ld8(br0 + 576 + kc), acc0);
            acc1 = mfma16(a, ld8(br1 + 576 + kc), acc1);
        }
    }

    {   // D layout: row = quad*4 + reg (in 16-row tile), col = l16
        int rl = w * 16 + quad * 4;
        #pragma unroll
        for (int r = 0; r < 4; ++r) {
            gt[rl + r][l16]      = acc0[r];
            gt[rl + r][16 + l16] = acc1[r];
        }
    }
    __syncthreads();

    // ---- phase 4: cell0 update + mu/sig partials ----
    #pragma unroll
    for (int pass = 0; pass < 2; ++pass) {
        int id = tid + pass * 256;   // 512 tasks: (bl, j)
        int bl = id >> 3, j = id & 7;
        int hidx = h_base + j;
        float gi = gt[bl][4 * j + 0] + bs0[hidx];
        float gf = gt[bl][4 * j + 1] + bs0[1024 + hidx];
        float gg = gt[bl][4 * j + 2] + bs0[2048 + hidx];
        float go = gt[bl][4 * j + 3] + bs0[3072 + hidx];
        int b = b_base + bl;
        float cold = c0[b * H_ + hidx];
        float cn = sigm(gf) * cold + sigm(gi) * tanh_(gg);
        float hn = sigm(go) * tanh_(cn);
        c0[b * H_ + hidx]  = cn;
        h0w[b * H_ + hidx] = f2bf(hn);
        float pmu = hn * muw[2 * hidx];
        float psg = hn * sgw[2 * hidx];
        #pragma unroll
        for (int off = 1; off < 8; off <<= 1) {
            pmu += __shfl_xor(pmu, off);
            psg += __shfl_xor(psg, off);
        }
        if (j == 0) {
            p0mu_w[b * 128 + wgn] = pmu;
            p0sg_w[b * 128 + wgn] = psg;
        }
    }
}

__global__ __launch_bounds__(256) void kB(
    const ushort_t* __restrict__ Wp1, const float* __restrict__ bs1,
    const ushort_t* __restrict__ h0c, const ushort_t* __restrict__ h1r, ushort_t* __restrict__ h1w,
    float* __restrict__ c1,
    const float* __restrict__ muw, const float* __restrict__ sgw,
    float* __restrict__ p1mu_w, float* __restrict__ p1sg_w, int t)
{
    __shared__ float gt[64][33];

    const int tid    = threadIdx.x;
    const int blk    = blockIdx.x;
    const int wgm    = blk >> 7;
    const int wgn    = blk & 127;
    const int b_base = wgm * 64;
    const int h_base = wgn * 8;

    const int w    = tid >> 6;
    const int lane = tid & 63;
    const int quad = lane >> 4;
    const int l16  = lane & 15;
    const int ko   = quad * 8;
    const int arow = b_base + w * 16 + l16;

    f32x4 acc0 = {0.f, 0.f, 0.f, 0.f};
    f32x4 acc1 = {0.f, 0.f, 0.f, 0.f};

    const ushort_t* a0  = h0c + (size_t)arow * H_ + ko;
    const ushort_t* br0 = Wp1 + ((size_t)(wgn * 32 + l16)) * 2048 + ko;
    const ushort_t* br1 = Wp1 + ((size_t)(wgn * 32 + 16 + l16)) * 2048 + ko;

    #pragma unroll 4
    for (int kc = 0; kc < H_; kc += 32) {
        bf16x8 a = ld8(a0 + kc);
        acc0 = mfma16(a, ld8(br0 + kc), acc0);
        acc1 = mfma16(a, ld8(br1 + kc), acc1);
    }
    if (t > 0) {
        const ushort_t* a1p = h1r + (size_t)arow * H_ + ko;
        #pragma unroll 4
        for (int kc = 0; kc < H_; kc += 32) {
            bf16x8 a = ld8(a1p + kc);
            acc0 = mfma16(a, ld8(br0 + 1024 + kc), acc0);
            acc1 = mfma16(a, ld8(br1 + 1024 + kc), acc1);
        }
    }

    {
        int rl = w * 16 + quad * 4;
        #pragma unroll
        for (int r = 0; r < 4; ++r) {
            gt[rl + r][l16]      = acc0[r];
            gt[rl + r][16 + l16] = acc1[r];
        }
    }
    __syncthreads();

    #pragma unroll
    for (int pass = 0; pass < 2; ++pass) {
        int id = tid + pass * 256;
        int bl = id >> 3, j = id & 7;
        int hidx = h_base + j;
        float gi = gt[bl][4 * j + 0] + bs1[hidx];
        float gf = gt[bl][4 * j + 1] + bs1[1024 + hidx];
        float gg = gt[bl][4 * j + 2] + bs1[2048 + hidx];
        float go = gt[bl][4 * j + 3] + bs1[3072 + hidx];
        int b = b_base + bl;
        float cold = c1[b * H_ + hidx];
        float cn = sigm(gf) * cold + sigm(gi) * tanh_(gg);
        float hn = sigm(go) * tanh_(cn);
        c1[b * H_ + hidx]  = cn;
        h1w[b * H_ + hidx] = f2bf(hn);
        float pmu = hn * muw[2 * hidx + 1];
        float psg = hn * sgw[2 * hidx + 1];
        #pragma unroll
        for (int off = 1; off < 8; off <<= 1) {
            pmu += __shfl_xor(pmu, off);
            psg += __shfl_xor(psg, off);
        }
        if (j == 0) {
            p1mu_w[b * 128 + wgn] = pmu;
            p1sg_w[b * 128 + wgn] = psg;
        }
    }
}

// final timestep's output
__global__ void kC(const float* __restrict__ p0mu, const float* __restrict__ p0sg,
                   const float* __restrict__ p1mu, const float* __restrict__ p1sg,
                   const float* __restrict__ mub, const float* __restrict__ sgb,
                   float* __restrict__ out)
{
    int tid = threadIdx.x;
    int b = tid >> 1, half = tid & 1;
    const float4* a = reinterpret_cast<const float4*>(p0mu + b * 128 + half * 64);
    const float4* c = reinterpret_cast<const float4*>(p1mu + b * 128 + half * 64);
    const float4* d = reinterpret_cast<const float4*>(p0sg + b * 128 + half * 64);
    const float4* e = reinterpret_cast<const float4*>(p1sg + b * 128 + half * 64);
    float sm = 0.f, ss = 0.f;
    #pragma unroll
    for (int i = 0; i < 16; ++i) {
        float4 x = a[i], y = c[i], z = d[i], u = e[i];
        sm += (x.x + x.y) + (x.z + x.w) + (y.x + y.y) + (y.z + y.w);
        ss += (z.x + z.y) + (z.z + z.w) + (u.x + u.y) + (u.z + u.w);
    }
    sm += __shfl_xor(sm, 1);
    ss += __shfl_xor(ss, 1);
    if (half == 0) {
        out[(b * T_ + (T_ - 1)) * 2 + 0] = sm + mub[0];
        out[(b * T_ + (T_ - 1)) * 2 + 1] = softp(ss + sgb[0]);
    }
}

// ---------------- host ----------------

extern "C" void kernel_launch(void* const* d_in, const int* in_sizes, int n_in,
                              void* d_out, int out_size, void* d_ws, size_t ws_size,
                              hipStream_t stream) {
    const float* feat = (const float*)d_in[0];
    const float* emb  = (const float*)d_in[1];
    const void*  mask = d_in[2];
    const float* Wih0 = (const float*)d_in[3];
    const float* Whh0 = (const float*)d_in[4];
    const float* bih0 = (const float*)d_in[5];
    const float* bhh0 = (const float*)d_in[6];
    const float* Wih1 = (const float*)d_in[7];
    const float* Whh1 = (const float*)d_in[8];
    const float* bih1 = (const float*)d_in[9];
    const float* bhh1 = (const float*)d_in[10];
    const float* Wtgt = (const float*)d_in[11];
    const float* btgt = (const float*)d_in[12];
    const float* muw  = (const float*)d_in[13];
    const float* mub  = (const float*)d_in[14];
    const float* sgw  = (const float*)d_in[15];
    const float* sgb  = (const float*)d_in[16];
    float* out = (float*)d_out;
    char* ws = (char*)d_ws;

    size_t off = 0;
    auto alloc = [&](size_t bytes) {
        size_t o = off;
        off = (off + bytes + 255) & ~(size_t)255;
        return o;
    };
    size_t o_flags = alloc(256);
    size_t o_c0    = alloc((size_t)B_ * H_ * 4);
    size_t o_c1    = alloc((size_t)B_ * H_ * 4);
    size_t zero_end = off;
    size_t o_h0    = alloc((size_t)2 * B_ * H_ * 2);
    size_t o_h1    = alloc((size_t)2 * B_ * H_ * 2);
    size_t o_p0mu  = alloc((size_t)2 * B_ * 128 * 4);
    size_t o_p0sg  = alloc((size_t)2 * B_ * 128 * 4);
    size_t o_p1mu  = alloc((size_t)2 * B_ * 128 * 4);
    size_t o_p1sg  = alloc((size_t)2 * B_ * 128 * 4);
    size_t o_bs0   = alloc((size_t)G4 * 4);
    size_t o_bs1   = alloc((size_t)G4 * 4);
    size_t o_Wp0   = alloc((size_t)G4 * 1600 * 2);
    size_t o_Wp1   = alloc((size_t)G4 * 2048 * 2);
    size_t o_fb    = alloc((size_t)T_ * B_ * FD * 2);
    (void)ws_size; (void)in_sizes; (void)n_in; (void)out_size;

    int*      flags = (int*)(ws + o_flags);
    float*    c0    = (float*)(ws + o_c0);
    float*    c1    = (float*)(ws + o_c1);
    ushort_t* h0    = (ushort_t*)(ws + o_h0);
    ushort_t* h1    = (ushort_t*)(ws + o_h1);
    float*    p0mu  = (float*)(ws + o_p0mu);
    float*    p0sg  = (float*)(ws + o_p0sg);
    float*    p1mu  = (float*)(ws + o_p1mu);
    float*    p1sg  = (float*)(ws + o_p1sg);
    float*    bs0   = (float*)(ws + o_bs0);
    float*    bs1   = (float*)(ws + o_bs1);
    ushort_t* Wp0   = (ushort_t*)(ws + o_Wp0);
    ushort_t* Wp1   = (ushort_t*)(ws + o_Wp1);
    ushort_t* fb    = (ushort_t*)(ws + o_fb);

    hipMemsetAsync(ws, 0, zero_end, stream);
    detect_mask<<<20, 256, 0, stream>>>((const unsigned*)mask, flags);
    pack0<<<1024, 256, 0, stream>>>(Wih0, Whh0, Wp0);
    pack1<<<1024, 256, 0, stream>>>(Wih1, Whh1, Wp1);
    bsumk<<<16, 256, 0, stream>>>(bih0, bhh0, bih1, bhh1, bs0, bs1);
    featconv<<<10240, 256, 0, stream>>>(feat, fb);

    const size_t PBUF = (size_t)B_ * 128;   // partial buffer elems per parity
    const size_t HBUF = (size_t)B_ * H_;

    for (int t = 0; t < T_; ++t) {
        int pc = t & 1, pp = pc ^ 1;
        kA<<<256, 256, 0, stream>>>(
            Wp0, bs0, fb, emb, mask, flags, Wtgt, btgt, muw, sgw, mub, sgb,
            c0, h0 + pp * HBUF, h0 + pc * HBUF,
            p0mu + pp * PBUF, p0sg + pp * PBUF, p1mu + pp * PBUF, p1sg + pp * PBUF,
            p0mu + pc * PBUF, p0sg + pc * PBUF,
            out, t);
        kB<<<256, 256, 0, stream>>>(
            Wp1, bs1, h0 + pc * HBUF, h1 + pp * HBUF, h1 + pc * HBUF,
            c1, muw, sgw,
            p1mu + pc * PBUF, p1sg + pc * PBUF, t);
    }
    // last step parity = (T_-1)&1 = 1
    kC<<<1, 256, 0, stream>>>(p0mu + 1 * PBUF, p0sg + 1 * PBUF,
                              p1mu + 1 * PBUF, p1sg + 1 * PBUF,
                              mub, sgb, out);
}